// Round 1
// baseline (29968.356 us; speedup 1.0000x reference)
//
#include <hip/hip_runtime.h>

#define H 384
#define DIN 256
#define EPS 1e-5f

// ---------------------------------------------------------------------------
// Generic tiled fp32 GEMM: C = A1@W1 (rows optionally scaled) [+ A2@W2] + bias
// A [Nr,K] row-major, W [K,M] row-major, C [Nr,M]. Optional relu.
// 64x64 tile per 256-thread block, 4x4 microtile per thread, K-panel = 16.
// K must be a multiple of 16 (true for 256/384/192/96).
// ---------------------------------------------------------------------------
__global__ __launch_bounds__(256) void gemm_fused(
    const float* __restrict__ A1, const float* __restrict__ W1,
    const float* __restrict__ rowscale,
    const float* __restrict__ A2, const float* __restrict__ W2,
    const float* __restrict__ bias, float* __restrict__ C,
    int Nr, int K, int M, int relu)
{
    __shared__ float As[16][68];
    __shared__ float Bs[16][68];
    const int t  = threadIdx.x;
    const int r0 = blockIdx.x * 64;
    const int c0 = blockIdx.y * 64;
    const int tx = t & 15;       // column group
    const int ty = t >> 4;       // row group
    float acc[4][4] = {};

    const int npass = (A2 != nullptr) ? 2 : 1;
    for (int pass = 0; pass < npass; ++pass) {
        const float* __restrict__ A  = pass ? A2 : A1;
        const float* __restrict__ W  = pass ? W2 : W1;
        const float* __restrict__ rs = pass ? nullptr : rowscale;
        for (int k0 = 0; k0 < K; k0 += 16) {
            // Load A tile: 64 rows x 16 k, 4 elements/thread, coalesced in k
            #pragma unroll
            for (int q = 0; q < 4; ++q) {
                int ei = t + q * 256;
                int r = ei >> 4, k = ei & 15;
                int gr = r0 + r;
                float v = 0.f;
                if (gr < Nr) {
                    v = A[(long)gr * K + k0 + k];
                    if (rs) v *= rs[gr];
                }
                As[k][r] = v;
            }
            // Load B tile: 16 k x 64 cols, coalesced in cols
            #pragma unroll
            for (int q = 0; q < 4; ++q) {
                int ei = t + q * 256;
                int k = ei >> 6, c = ei & 63;
                int gc = c0 + c;
                float v = 0.f;
                if (gc < M) v = W[(long)(k0 + k) * M + gc];
                Bs[k][c] = v;
            }
            __syncthreads();
            #pragma unroll
            for (int kk = 0; kk < 16; ++kk) {
                const float4 a = *(const float4*)(&As[kk][ty << 2]);
                const float4 b = *(const float4*)(&Bs[kk][tx << 2]);
                const float av[4] = {a.x, a.y, a.z, a.w};
                const float bv[4] = {b.x, b.y, b.z, b.w};
                #pragma unroll
                for (int i = 0; i < 4; ++i)
                    #pragma unroll
                    for (int j = 0; j < 4; ++j)
                        acc[i][j] += av[i] * bv[j];
            }
            __syncthreads();
        }
    }

    #pragma unroll
    for (int i = 0; i < 4; ++i) {
        int gr = r0 + (ty << 2) + i;
        if (gr >= Nr) continue;
        #pragma unroll
        for (int j = 0; j < 4; ++j) {
            int gc = c0 + (tx << 2) + j;
            if (gc >= M) continue;
            float v = acc[i][j] + bias[gc];
            if (relu) v = fmaxf(v, 0.f);
            C[(long)gr * M + gc] = v;
        }
    }
}

// ---------------------------------------------------------------------------
// Edge degree count (over col) and inversion
// ---------------------------------------------------------------------------
__global__ void count_edges(const int* __restrict__ col, float* __restrict__ cnt, int E)
{
    int e = blockIdx.x * 256 + threadIdx.x;
    if (e < E) atomicAdd(&cnt[col[e]], 1.0f);
}

__global__ void invert_cnt(float* __restrict__ cnt, int n)
{
    int i = blockIdx.x * 256 + threadIdx.x;
    if (i < n) cnt[i] = 1.0f / fmaxf(cnt[i], 1.0f);
}

// ---------------------------------------------------------------------------
// Scatter-sum aggregation: agg[col[e]] += h[row[e]]  (one float4 per thread)
// ---------------------------------------------------------------------------
__global__ void scatter_agg(const float* __restrict__ h,
                            const int* __restrict__ row, const int* __restrict__ col,
                            float* __restrict__ agg, int E)
{
    unsigned int idx = blockIdx.x * 256u + threadIdx.x;
    unsigned int total = (unsigned int)E * 96u;
    if (idx >= total) return;
    unsigned int e = idx / 96u;
    unsigned int j = idx - e * 96u;
    int r = row[e], c = col[e];
    const float4 v = *(const float4*)(&h[(long)r * H + j * 4]);
    float* dst = &agg[(long)c * H + j * 4];
    atomicAdd(dst + 0, v.x);
    atomicAdd(dst + 1, v.y);
    atomicAdd(dst + 2, v.z);
    atomicAdd(dst + 3, v.w);
}

// ---------------------------------------------------------------------------
// BatchNorm: column-wise sum/sumsq partials (block of H threads), atomics out
// ---------------------------------------------------------------------------
__global__ void bn_stats(const float* __restrict__ X, float* __restrict__ sums,
                         float* __restrict__ sumsq, int Nr)
{
    int j = threadIdx.x;           // 0..383, one column per thread
    float s = 0.f, ss = 0.f;
    for (int i = blockIdx.x; i < Nr; i += gridDim.x) {
        float v = X[(long)i * H + j];
        s += v;
        ss += v * v;
    }
    atomicAdd(&sums[j], s);
    atomicAdd(&sumsq[j], ss);
}

__global__ void bn_finalize(const float* __restrict__ sums, const float* __restrict__ sumsq,
                            const float* __restrict__ g, const float* __restrict__ b,
                            float* __restrict__ scale, float* __restrict__ shift, int Nr)
{
    int j = threadIdx.x;
    if (j < H) {
        float mu  = sums[j] / (float)Nr;
        float var = sumsq[j] / (float)Nr - mu * mu;
        float sc  = g[j] * rsqrtf(fmaxf(var, 0.f) + EPS);
        scale[j] = sc;
        shift[j] = b[j] - mu * sc;
    }
}

// out = relu(X*scale + shift) [+ S]      (float4 per thread)
__global__ void bn_apply(const float* __restrict__ X, const float* __restrict__ scale,
                         const float* __restrict__ shift, const float* __restrict__ S,
                         float* __restrict__ out, int total4)
{
    int idx = blockIdx.x * 256 + threadIdx.x;
    if (idx >= total4) return;
    int base = idx * 4;
    int j = base % H;
    float4 v = *(const float4*)(&X[base]);
    float4 o;
    o.x = fmaxf(v.x * scale[j + 0] + shift[j + 0], 0.f);
    o.y = fmaxf(v.y * scale[j + 1] + shift[j + 1], 0.f);
    o.z = fmaxf(v.z * scale[j + 2] + shift[j + 2], 0.f);
    o.w = fmaxf(v.w * scale[j + 3] + shift[j + 3], 0.f);
    if (S) {
        float4 s4 = *(const float4*)(&S[base]);
        o.x += s4.x; o.y += s4.y; o.z += s4.z; o.w += s4.w;
    }
    *(float4*)(&out[base]) = o;
}

// ---------------------------------------------------------------------------
extern "C" void kernel_launch(void* const* d_in, const int* in_sizes, int n_in,
                              void* d_out, int out_size, void* d_ws, size_t ws_size,
                              hipStream_t stream)
{
    const float* x     = (const float*)d_in[0];
    const int*   ei    = (const int*)d_in[1];
    const float* W_in  = (const float*)d_in[2];
    const float* b_in  = (const float*)d_in[3];
    const float* bn0_g = (const float*)d_in[4];
    const float* bn0_b = (const float*)d_in[5];
    const float* Wl    = (const float*)d_in[6];
    const float* bl    = (const float*)d_in[7];
    const float* Wr    = (const float*)d_in[8];
    const float* bn_g  = (const float*)d_in[9];
    const float* bn_b  = (const float*)d_in[10];
    const float* Wskip = (const float*)d_in[11];
    const float* bskip = (const float*)d_in[12];
    const float* W1    = (const float*)d_in[13];
    const float* b1    = (const float*)d_in[14];
    const float* W2    = (const float*)d_in[15];
    const float* b2    = (const float*)d_in[16];
    const float* W3    = (const float*)d_in[17];
    const float* b3    = (const float*)d_in[18];

    const int N = in_sizes[0] / DIN;
    const int E = in_sizes[1] / 2;
    const int* row = ei;
    const int* col = ei + E;

    const long NH = (long)N * H;
    float* h       = (float*)d_ws;
    float* agg     = h + NH;
    float* tmp     = agg + NH;
    float* inv     = tmp + NH;
    float* bnsum   = inv + N;
    float* bnsq    = bnsum + H;
    float* bnscale = bnsq + H;
    float* bnshift = bnscale + H;
    float* out     = (float*)d_out;

    dim3 blk(256);
    const int rgrid = (N + 63) / 64;
    const int app_grid = (int)((NH / 4 + 255) / 256);

    // degree -> inv_cnt
    hipMemsetAsync(inv, 0, N * sizeof(float), stream);
    count_edges<<<(E + 255) / 256, blk, 0, stream>>>(col, inv, E);
    invert_cnt<<<(N + 255) / 256, blk, 0, stream>>>(inv, N);

    // ---- input layer: h = relu(BN0(x @ W_in + b_in))
    gemm_fused<<<dim3(rgrid, (H + 63) / 64), blk, 0, stream>>>(
        x, W_in, nullptr, nullptr, nullptr, b_in, tmp, N, DIN, H, 0);
    hipMemsetAsync(bnsum, 0, 2 * H * sizeof(float), stream);
    bn_stats<<<256, H, 0, stream>>>(tmp, bnsum, bnsq, N);
    bn_finalize<<<1, H, 0, stream>>>(bnsum, bnsq, bn0_g, bn0_b, bnscale, bnshift, N);
    bn_apply<<<app_grid, blk, 0, stream>>>(tmp, bnscale, bnshift, nullptr, h, (int)(NH / 4));

    // ---- 6 SAGE layers
    int skip_idx = 0;
    for (int i = 0; i < 6; ++i) {
        hipMemsetAsync(agg, 0, NH * sizeof(float), stream);
        unsigned int total = (unsigned int)E * 96u;
        scatter_agg<<<(total + 255) / 256, blk, 0, stream>>>(h, row, col, agg, E);

        // tmp = (inv∘agg)@Wl[i] + h@Wr[i] + bl[i]
        gemm_fused<<<dim3(rgrid, H / 64), blk, 0, stream>>>(
            agg, Wl + (long)i * H * H, inv, h, Wr + (long)i * H * H,
            bl + i * H, tmp, N, H, H, 0);

        hipMemsetAsync(bnsum, 0, 2 * H * sizeof(float), stream);
        bn_stats<<<256, H, 0, stream>>>(tmp, bnsum, bnsq, N);
        bn_finalize<<<1, H, 0, stream>>>(bnsum, bnsq, bn_g + i * H, bn_b + i * H,
                                         bnscale, bnshift, N);

        const float* S = nullptr;
        if ((i & 1) == 1) {
            // skip branch: S = identity(h) @ Wskip + bskip  (into agg, now free)
            gemm_fused<<<dim3(rgrid, H / 64), blk, 0, stream>>>(
                h, Wskip + (long)skip_idx * H * H, nullptr, nullptr, nullptr,
                bskip + skip_idx * H, agg, N, H, H, 0);
            skip_idx++;
            S = agg;
        }
        // h = relu(BN(tmp)) [+ S]   (overwrites h; identity no longer needed)
        bn_apply<<<app_grid, blk, 0, stream>>>(tmp, bnscale, bnshift, S, h, (int)(NH / 4));
    }

    // ---- MLP head (h preserved as embeddings)
    float* m1 = agg;   // [N,192]
    float* m2 = tmp;   // [N,96]
    gemm_fused<<<dim3(rgrid, (192 + 63) / 64), blk, 0, stream>>>(
        h, W1, nullptr, nullptr, nullptr, b1, m1, N, H, 192, 1);
    gemm_fused<<<dim3(rgrid, (96 + 63) / 64), blk, 0, stream>>>(
        m1, W2, nullptr, nullptr, nullptr, b2, m2, N, 192, 96, 1);
    gemm_fused<<<dim3(rgrid, 1), blk, 0, stream>>>(
        m2, W3, nullptr, nullptr, nullptr, b3, out, N, 96, 2, 0);

    // embeddings after the logits block
    hipMemcpyAsync(out + (long)N * 2, h, NH * sizeof(float),
                   hipMemcpyDeviceToDevice, stream);
}

// Round 2
// 6661.561 us; speedup vs baseline: 4.4987x; 4.4987x over previous
//
#include <hip/hip_runtime.h>

#define H 384
#define DIN 256
#define EPS 1e-5f

// ---------------------------------------------------------------------------
// Generic tiled fp32 GEMM: C = A1@W1 [+ A2@W2] + bias. Optional relu.
// 64x64 tile per 256-thread block, 4x4 microtile per thread, K-panel = 16.
// ---------------------------------------------------------------------------
__global__ __launch_bounds__(256) void gemm_fused(
    const float* __restrict__ A1, const float* __restrict__ W1,
    const float* __restrict__ A2, const float* __restrict__ W2,
    const float* __restrict__ bias, float* __restrict__ C,
    int Nr, int K, int M, int relu)
{
    __shared__ float As[16][68];
    __shared__ float Bs[16][68];
    const int t  = threadIdx.x;
    const int r0 = blockIdx.x * 64;
    const int c0 = blockIdx.y * 64;
    const int tx = t & 15;       // column group
    const int ty = t >> 4;       // row group
    float acc[4][4] = {};

    const int npass = (A2 != nullptr) ? 2 : 1;
    for (int pass = 0; pass < npass; ++pass) {
        const float* __restrict__ A = pass ? A2 : A1;
        const float* __restrict__ W = pass ? W2 : W1;
        for (int k0 = 0; k0 < K; k0 += 16) {
            #pragma unroll
            for (int q = 0; q < 4; ++q) {
                int ei = t + q * 256;
                int r = ei >> 4, k = ei & 15;
                int gr = r0 + r;
                float v = 0.f;
                if (gr < Nr) v = A[(long)gr * K + k0 + k];
                As[k][r] = v;
            }
            #pragma unroll
            for (int q = 0; q < 4; ++q) {
                int ei = t + q * 256;
                int k = ei >> 6, c = ei & 63;
                int gc = c0 + c;
                float v = 0.f;
                if (gc < M) v = W[(long)(k0 + k) * M + gc];
                Bs[k][c] = v;
            }
            __syncthreads();
            #pragma unroll
            for (int kk = 0; kk < 16; ++kk) {
                const float4 a = *(const float4*)(&As[kk][ty << 2]);
                const float4 b = *(const float4*)(&Bs[kk][tx << 2]);
                const float av[4] = {a.x, a.y, a.z, a.w};
                const float bv[4] = {b.x, b.y, b.z, b.w};
                #pragma unroll
                for (int i = 0; i < 4; ++i)
                    #pragma unroll
                    for (int j = 0; j < 4; ++j)
                        acc[i][j] += av[i] * bv[j];
            }
            __syncthreads();
        }
    }

    #pragma unroll
    for (int i = 0; i < 4; ++i) {
        int gr = r0 + (ty << 2) + i;
        if (gr >= Nr) continue;
        #pragma unroll
        for (int j = 0; j < 4; ++j) {
            int gc = c0 + (tx << 2) + j;
            if (gc >= M) continue;
            float v = acc[i][j] + bias[gc];
            if (relu) v = fmaxf(v, 0.f);
            C[(long)gr * M + gc] = v;
        }
    }
}

// ---------------------------------------------------------------------------
// CSR construction: count -> exclusive scan (1 block) -> fill
// ---------------------------------------------------------------------------
__global__ void count_edges_i(const int* __restrict__ col, int* __restrict__ cnt, int E)
{
    int e = blockIdx.x * 256 + threadIdx.x;
    if (e < E) atomicAdd(&cnt[col[e]], 1);
}

__global__ __launch_bounds__(1024) void exscan_csr(const int* __restrict__ cnt,
                                                   int* __restrict__ offs, int n)
{
    __shared__ int s[1024];
    const int t = threadIdx.x;
    const int chunk = (n + 1023) >> 10;
    int lo = t * chunk, hi = lo + chunk;
    if (lo > n) lo = n;
    if (hi > n) hi = n;
    int sum = 0;
    for (int i = lo; i < hi; ++i) sum += cnt[i];
    s[t] = sum;
    __syncthreads();
    for (int d = 1; d < 1024; d <<= 1) {
        int o = (t >= d) ? s[t - d] : 0;
        __syncthreads();
        s[t] += o;
        __syncthreads();
    }
    int base = (t == 0) ? 0 : s[t - 1];
    for (int i = lo; i < hi; ++i) { offs[i] = base; base += cnt[i]; }
    if (t == 1023) offs[n] = s[1023];
}

__global__ void fill_csr(const int* __restrict__ row, const int* __restrict__ col,
                         const int* __restrict__ offs, int* __restrict__ cursor,
                         int* __restrict__ csr_rows, int E)
{
    int e = blockIdx.x * 256 + threadIdx.x;
    if (e < E) {
        int c = col[e];
        int p = offs[c] + atomicAdd(&cursor[c], 1);
        csr_rows[p] = row[e];
    }
}

__global__ void inv_from_cnt(const int* __restrict__ cnt, float* __restrict__ inv, int n)
{
    int i = blockIdx.x * 256 + threadIdx.x;
    if (i < n) inv[i] = 1.0f / fmaxf((float)cnt[i], 1.0f);
}

// ---------------------------------------------------------------------------
// CSR gather-mean: agg[c][:] = inv[c] * sum_{e in [offs[c],offs[c+1])} h[rows[e]][:]
// One block per node, 384 threads = one feature each (coalesced 1536B/row).
// ---------------------------------------------------------------------------
__global__ __launch_bounds__(384) void agg_gather(
    const float* __restrict__ h, const int* __restrict__ csr_rows,
    const int* __restrict__ offs, const float* __restrict__ inv,
    float* __restrict__ agg)
{
    const int c = blockIdx.x;
    const int j = threadIdx.x;
    const int lo = offs[c], hi = offs[c + 1];
    float s = 0.f;
    int e = lo;
    for (; e + 1 < hi; e += 2) {
        int r0 = csr_rows[e], r1 = csr_rows[e + 1];
        s += h[(long)r0 * H + j];
        s += h[(long)r1 * H + j];
    }
    if (e < hi) s += h[(long)csr_rows[e] * H + j];
    agg[(long)c * H + j] = s * inv[c];
}

// ---------------------------------------------------------------------------
// BatchNorm
// ---------------------------------------------------------------------------
__global__ void bn_stats(const float* __restrict__ X, float* __restrict__ sums,
                         float* __restrict__ sumsq, int Nr)
{
    int j = threadIdx.x;
    float s = 0.f, ss = 0.f;
    for (int i = blockIdx.x; i < Nr; i += gridDim.x) {
        float v = X[(long)i * H + j];
        s += v;
        ss += v * v;
    }
    atomicAdd(&sums[j], s);
    atomicAdd(&sumsq[j], ss);
}

__global__ void bn_finalize(const float* __restrict__ sums, const float* __restrict__ sumsq,
                            const float* __restrict__ g, const float* __restrict__ b,
                            float* __restrict__ scale, float* __restrict__ shift, int Nr)
{
    int j = threadIdx.x;
    if (j < H) {
        float mu  = sums[j] / (float)Nr;
        float var = sumsq[j] / (float)Nr - mu * mu;
        float sc  = g[j] * rsqrtf(fmaxf(var, 0.f) + EPS);
        scale[j] = sc;
        shift[j] = b[j] - mu * sc;
    }
}

__global__ void bn_apply(const float* __restrict__ X, const float* __restrict__ scale,
                         const float* __restrict__ shift, const float* __restrict__ S,
                         float* __restrict__ out, int total4)
{
    int idx = blockIdx.x * 256 + threadIdx.x;
    if (idx >= total4) return;
    int base = idx * 4;
    int j = base % H;
    float4 v = *(const float4*)(&X[base]);
    float4 o;
    o.x = fmaxf(v.x * scale[j + 0] + shift[j + 0], 0.f);
    o.y = fmaxf(v.y * scale[j + 1] + shift[j + 1], 0.f);
    o.z = fmaxf(v.z * scale[j + 2] + shift[j + 2], 0.f);
    o.w = fmaxf(v.w * scale[j + 3] + shift[j + 3], 0.f);
    if (S) {
        float4 s4 = *(const float4*)(&S[base]);
        o.x += s4.x; o.y += s4.y; o.z += s4.z; o.w += s4.w;
    }
    *(float4*)(&out[base]) = o;
}

// ---------------------------------------------------------------------------
extern "C" void kernel_launch(void* const* d_in, const int* in_sizes, int n_in,
                              void* d_out, int out_size, void* d_ws, size_t ws_size,
                              hipStream_t stream)
{
    const float* x     = (const float*)d_in[0];
    const int*   ei    = (const int*)d_in[1];
    const float* W_in  = (const float*)d_in[2];
    const float* b_in  = (const float*)d_in[3];
    const float* bn0_g = (const float*)d_in[4];
    const float* bn0_b = (const float*)d_in[5];
    const float* Wl    = (const float*)d_in[6];
    const float* bl    = (const float*)d_in[7];
    const float* Wr    = (const float*)d_in[8];
    const float* bn_g  = (const float*)d_in[9];
    const float* bn_b  = (const float*)d_in[10];
    const float* Wskip = (const float*)d_in[11];
    const float* bskip = (const float*)d_in[12];
    const float* W1    = (const float*)d_in[13];
    const float* b1    = (const float*)d_in[14];
    const float* W2    = (const float*)d_in[15];
    const float* b2    = (const float*)d_in[16];
    const float* W3    = (const float*)d_in[17];
    const float* b3    = (const float*)d_in[18];

    const int N = in_sizes[0] / DIN;
    const int E = in_sizes[1] / 2;
    const int* row = ei;
    const int* col = ei + E;

    const long NH = (long)N * H;
    float* h        = (float*)d_ws;
    float* agg      = h + NH;
    float* tmp      = agg + NH;
    float* inv      = tmp + NH;
    float* bnsum    = inv + N;
    float* bnsq     = bnsum + H;
    float* bnscale  = bnsq + H;
    float* bnshift  = bnscale + H;
    int*   offs     = (int*)(bnshift + H);       // N+1 ints
    int*   csr_rows = offs + (N + 1);            // E ints
    // transient CSR scratch aliased into tmp (unused until first GEMM)
    int*   cnt      = (int*)tmp;                 // N ints
    int*   cursor   = cnt + N;                   // N ints
    float* out      = (float*)d_out;

    dim3 blk(256);
    const int rgrid = (N + 63) / 64;
    const int app_grid = (int)((NH / 4 + 255) / 256);

    // ---- build CSR (per call; ws is re-poisoned between calls)
    hipMemsetAsync(cnt, 0, 2 * N * sizeof(int), stream);   // cnt + cursor
    count_edges_i<<<(E + 255) / 256, blk, 0, stream>>>(col, cnt, E);
    exscan_csr<<<1, 1024, 0, stream>>>(cnt, offs, N);
    inv_from_cnt<<<(N + 255) / 256, blk, 0, stream>>>(cnt, inv, N);
    fill_csr<<<(E + 255) / 256, blk, 0, stream>>>(row, col, offs, cursor, csr_rows, E);

    // ---- input layer: h = relu(BN0(x @ W_in + b_in))
    gemm_fused<<<dim3(rgrid, (H + 63) / 64), blk, 0, stream>>>(
        x, W_in, nullptr, nullptr, b_in, tmp, N, DIN, H, 0);
    hipMemsetAsync(bnsum, 0, 2 * H * sizeof(float), stream);
    bn_stats<<<256, H, 0, stream>>>(tmp, bnsum, bnsq, N);
    bn_finalize<<<1, H, 0, stream>>>(bnsum, bnsq, bn0_g, bn0_b, bnscale, bnshift, N);
    bn_apply<<<app_grid, blk, 0, stream>>>(tmp, bnscale, bnshift, nullptr, h, (int)(NH / 4));

    // ---- 6 SAGE layers
    int skip_idx = 0;
    for (int i = 0; i < 6; ++i) {
        agg_gather<<<N, 384, 0, stream>>>(h, csr_rows, offs, inv, agg);

        // tmp = agg@Wl[i] + h@Wr[i] + bl[i]
        gemm_fused<<<dim3(rgrid, H / 64), blk, 0, stream>>>(
            agg, Wl + (long)i * H * H, h, Wr + (long)i * H * H,
            bl + i * H, tmp, N, H, H, 0);

        hipMemsetAsync(bnsum, 0, 2 * H * sizeof(float), stream);
        bn_stats<<<256, H, 0, stream>>>(tmp, bnsum, bnsq, N);
        bn_finalize<<<1, H, 0, stream>>>(bnsum, bnsq, bn_g + i * H, bn_b + i * H,
                                         bnscale, bnshift, N);

        const float* S = nullptr;
        if ((i & 1) == 1) {
            gemm_fused<<<dim3(rgrid, H / 64), blk, 0, stream>>>(
                h, Wskip + (long)skip_idx * H * H, nullptr, nullptr,
                bskip + skip_idx * H, agg, N, H, H, 0);
            skip_idx++;
            S = agg;
        }
        bn_apply<<<app_grid, blk, 0, stream>>>(tmp, bnscale, bnshift, S, h, (int)(NH / 4));
    }

    // ---- MLP head (h preserved as embeddings)
    float* m1 = agg;   // [N,192]
    float* m2 = tmp;   // [N,96]
    gemm_fused<<<dim3(rgrid, (192 + 63) / 64), blk, 0, stream>>>(
        h, W1, nullptr, nullptr, b1, m1, N, H, 192, 1);
    gemm_fused<<<dim3(rgrid, (96 + 63) / 64), blk, 0, stream>>>(
        m1, W2, nullptr, nullptr, b2, m2, N, 192, 96, 1);
    gemm_fused<<<dim3(rgrid, 1), blk, 0, stream>>>(
        m2, W3, nullptr, nullptr, b3, out, N, 96, 2, 0);

    hipMemcpyAsync(out + (long)N * 2, h, NH * sizeof(float),
                   hipMemcpyDeviceToDevice, stream);
}

// Round 3
// 2229.493 us; speedup vs baseline: 13.4418x; 2.9879x over previous
//
#include <hip/hip_runtime.h>

#define H 384
#define EPS 1e-5f

typedef __attribute__((ext_vector_type(8))) short bf8v;   // 8 bf16 in 4 VGPRs
typedef __attribute__((ext_vector_type(4))) float f32x4;

__device__ __forceinline__ float b2f(unsigned short b) {
    return __builtin_bit_cast(float, (unsigned)b << 16);
}
__device__ __forceinline__ unsigned short f2b(float f) {
    unsigned u = __builtin_bit_cast(unsigned, f);
    u += 0x7FFFu + ((u >> 16) & 1u);          // RNE
    return (unsigned short)(u >> 16);
}

// ---------------------------------------------------------------------------
// bf16 MFMA GEMM: C = A1@W1t^T [+ A2@W2t^T] + bias, optional relu.
// A [Nr,K] bf16 row-major; Wt [M,K] bf16 row-major (pre-transposed weights).
// Output to Cf (fp32) or Cb (bf16). 128x128 tile, 4 waves, 16x16x32 MFMA.
// K must be a multiple of 32.
// ---------------------------------------------------------------------------
__global__ __launch_bounds__(256) void gemm_mfma(
    const unsigned short* __restrict__ A1, const unsigned short* __restrict__ W1t,
    const unsigned short* __restrict__ A2, const unsigned short* __restrict__ W2t,
    const float* __restrict__ bias, float* __restrict__ Cf,
    unsigned short* __restrict__ Cb, int Nr, int K, int M, int relu)
{
    __shared__ unsigned short As[128][40];   // +8 pad: 80B row stride
    __shared__ unsigned short Bs[128][40];
    const int t = threadIdx.x;
    const int wave = t >> 6, lane = t & 63;
    const int wr = (wave >> 1) * 64, wc = (wave & 1) * 64;
    const int r0 = blockIdx.x * 128, c0 = blockIdx.y * 128;
    const int lm = lane & 15, lq = lane >> 4;
    f32x4 acc[4][4] = {};

    const int npass = (A2 != nullptr) ? 2 : 1;
    for (int pass = 0; pass < npass; ++pass) {
        const unsigned short* __restrict__ A = pass ? A2 : A1;
        const unsigned short* __restrict__ W = pass ? W2t : W1t;
        for (int k0 = 0; k0 < K; k0 += 32) {
            #pragma unroll
            for (int q = 0; q < 2; ++q) {           // As: 512 chunks of 8 bf16
                int c = t + q * 256;
                int r = c >> 2, ko = (c & 3) * 8;
                int gr = r0 + r; if (gr >= Nr) gr = Nr - 1;
                bf8v v = *(const bf8v*)(A + (long)gr * K + k0 + ko);
                *(bf8v*)&As[r][ko] = v;
            }
            #pragma unroll
            for (int q = 0; q < 2; ++q) {           // Bs: 512 chunks
                int c = t + q * 256;
                int r = c >> 2, ko = (c & 3) * 8;
                int gc = c0 + r; if (gc >= M) gc = M - 1;
                bf8v v = *(const bf8v*)(W + (long)gc * K + k0 + ko);
                *(bf8v*)&Bs[r][ko] = v;
            }
            __syncthreads();
            bf8v af[4], bf[4];
            #pragma unroll
            for (int i = 0; i < 4; ++i)
                af[i] = *(const bf8v*)&As[wr + i * 16 + lm][lq * 8];
            #pragma unroll
            for (int j = 0; j < 4; ++j)
                bf[j] = *(const bf8v*)&Bs[wc + j * 16 + lm][lq * 8];
            #pragma unroll
            for (int i = 0; i < 4; ++i)
                #pragma unroll
                for (int j = 0; j < 4; ++j)
                    acc[i][j] = __builtin_amdgcn_mfma_f32_16x16x32_bf16(
                        af[i], bf[j], acc[i][j], 0, 0, 0);
            __syncthreads();
        }
    }

    #pragma unroll
    for (int i = 0; i < 4; ++i) {
        #pragma unroll
        for (int j = 0; j < 4; ++j) {
            int col = c0 + wc + j * 16 + lm;
            if (col >= M) continue;
            float bi = bias[col];
            #pragma unroll
            for (int r = 0; r < 4; ++r) {
                int rowi = r0 + wr + i * 16 + lq * 4 + r;
                if (rowi >= Nr) continue;
                float v = acc[i][j][r] + bi;
                if (relu) v = fmaxf(v, 0.f);
                if (Cf) Cf[(long)rowi * M + col] = v;
                else    Cb[(long)rowi * M + col] = f2b(v);
            }
        }
    }
}

// ---------------------------------------------------------------------------
// Weight convert+transpose: W [L][K][M] fp32 -> Wt [L][M][K] bf16
// ---------------------------------------------------------------------------
__global__ void wt_convert(const float* __restrict__ W, unsigned short* __restrict__ Wt,
                           int total, int K, int M)
{
    int idx = blockIdx.x * 256 + threadIdx.x;
    if (idx >= total) return;
    int l = idx / (K * M), rem = idx - l * K * M;
    int k = rem / M, m = rem - k * M;
    Wt[(long)l * K * M + (long)m * K + k] = f2b(W[idx]);
}

__global__ void f2b_vec(const float* __restrict__ X, unsigned short* __restrict__ Y, int n4)
{
    int idx = blockIdx.x * 256 + threadIdx.x;
    if (idx >= n4) return;
    float4 v = *(const float4*)(X + idx * 4);
    ushort4 o = {f2b(v.x), f2b(v.y), f2b(v.z), f2b(v.w)};
    *(ushort4*)(Y + idx * 4) = o;
}

__global__ void b2f_vec(const unsigned short* __restrict__ X, float* __restrict__ Y, int n4)
{
    int idx = blockIdx.x * 256 + threadIdx.x;
    if (idx >= n4) return;
    ushort4 v = *(const ushort4*)(X + idx * 4);
    float4 o = {b2f(v.x), b2f(v.y), b2f(v.z), b2f(v.w)};
    *(float4*)(Y + idx * 4) = o;
}

// ---------------------------------------------------------------------------
// CSR construction
// ---------------------------------------------------------------------------
__global__ void count_edges_i(const int* __restrict__ col, int* __restrict__ cnt, int E)
{
    int e = blockIdx.x * 256 + threadIdx.x;
    if (e < E) atomicAdd(&cnt[col[e]], 1);
}

__global__ __launch_bounds__(1024) void exscan_csr(const int* __restrict__ cnt,
                                                   int* __restrict__ offs, int n)
{
    __shared__ int s[1024];
    const int t = threadIdx.x;
    const int chunk = (n + 1023) >> 10;
    int lo = t * chunk, hi = lo + chunk;
    if (lo > n) lo = n;
    if (hi > n) hi = n;
    int sum = 0;
    for (int i = lo; i < hi; ++i) sum += cnt[i];
    s[t] = sum;
    __syncthreads();
    for (int d = 1; d < 1024; d <<= 1) {
        int o = (t >= d) ? s[t - d] : 0;
        __syncthreads();
        s[t] += o;
        __syncthreads();
    }
    int base = (t == 0) ? 0 : s[t - 1];
    for (int i = lo; i < hi; ++i) { offs[i] = base; base += cnt[i]; }
    if (t == 1023) offs[n] = s[1023];
}

__global__ void fill_csr(const int* __restrict__ row, const int* __restrict__ col,
                         const int* __restrict__ offs, int* __restrict__ cursor,
                         int* __restrict__ csr_rows, int E)
{
    int e = blockIdx.x * 256 + threadIdx.x;
    if (e < E) {
        int c = col[e];
        int p = offs[c] + atomicAdd(&cursor[c], 1);
        csr_rows[p] = row[e];
    }
}

__global__ void inv_from_cnt(const int* __restrict__ cnt, float* __restrict__ inv, int n)
{
    int i = blockIdx.x * 256 + threadIdx.x;
    if (i < n) inv[i] = 1.0f / fmaxf((float)cnt[i], 1.0f);
}

// ---------------------------------------------------------------------------
// CSR gather-mean in bf16: 4 nodes/block, 96 lanes/node, 4 features/lane
// ---------------------------------------------------------------------------
__global__ __launch_bounds__(384) void agg_gather(
    const unsigned short* __restrict__ hb, const int* __restrict__ csr_rows,
    const int* __restrict__ offs, const float* __restrict__ inv,
    unsigned short* __restrict__ aggb, int N)
{
    int node = blockIdx.x * 4 + threadIdx.x / 96;
    int lane = threadIdx.x % 96;
    if (node >= N) return;
    const int lo = offs[node], hi = offs[node + 1];
    float s0 = 0.f, s1 = 0.f, s2 = 0.f, s3 = 0.f;
    int e = lo;
    for (; e + 1 < hi; e += 2) {
        int r0 = csr_rows[e], r1 = csr_rows[e + 1];
        ushort4 v0 = *(const ushort4*)(hb + (long)r0 * H + lane * 4);
        ushort4 v1 = *(const ushort4*)(hb + (long)r1 * H + lane * 4);
        s0 += b2f(v0.x) + b2f(v1.x);
        s1 += b2f(v0.y) + b2f(v1.y);
        s2 += b2f(v0.z) + b2f(v1.z);
        s3 += b2f(v0.w) + b2f(v1.w);
    }
    if (e < hi) {
        ushort4 v = *(const ushort4*)(hb + (long)csr_rows[e] * H + lane * 4);
        s0 += b2f(v.x); s1 += b2f(v.y); s2 += b2f(v.z); s3 += b2f(v.w);
    }
    float sc = inv[node];
    ushort4 o = {f2b(s0 * sc), f2b(s1 * sc), f2b(s2 * sc), f2b(s3 * sc)};
    *(ushort4*)(aggb + (long)node * H + lane * 4) = o;
}

// ---------------------------------------------------------------------------
// BatchNorm
// ---------------------------------------------------------------------------
__global__ void bn_stats(const float* __restrict__ X, float* __restrict__ sums,
                         float* __restrict__ sumsq, int Nr)
{
    int j = threadIdx.x;
    float s = 0.f, ss = 0.f;
    for (int i = blockIdx.x; i < Nr; i += gridDim.x) {
        float v = X[(long)i * H + j];
        s += v;
        ss += v * v;
    }
    atomicAdd(&sums[j], s);
    atomicAdd(&sumsq[j], ss);
}

__global__ void bn_finalize(const float* __restrict__ sums, const float* __restrict__ sumsq,
                            const float* __restrict__ g, const float* __restrict__ b,
                            float* __restrict__ scale, float* __restrict__ shift, int Nr)
{
    int j = threadIdx.x;
    if (j < H) {
        float mu  = sums[j] / (float)Nr;
        float var = sumsq[j] / (float)Nr - mu * mu;
        float sc  = g[j] * rsqrtf(fmaxf(var, 0.f) + EPS);
        scale[j] = sc;
        shift[j] = b[j] - mu * sc;
    }
}

// out_bf16 = relu(X*scale + shift) [+ S_bf16]
__global__ void bn_apply(const float* __restrict__ X, const float* __restrict__ scale,
                         const float* __restrict__ shift, const unsigned short* __restrict__ S,
                         unsigned short* __restrict__ out, int total4)
{
    int idx = blockIdx.x * 256 + threadIdx.x;
    if (idx >= total4) return;
    int base = idx * 4;
    int j = base % H;
    float4 v = *(const float4*)(&X[base]);
    float o0 = fmaxf(v.x * scale[j + 0] + shift[j + 0], 0.f);
    float o1 = fmaxf(v.y * scale[j + 1] + shift[j + 1], 0.f);
    float o2 = fmaxf(v.z * scale[j + 2] + shift[j + 2], 0.f);
    float o3 = fmaxf(v.w * scale[j + 3] + shift[j + 3], 0.f);
    if (S) {
        ushort4 s4 = *(const ushort4*)(S + base);
        o0 += b2f(s4.x); o1 += b2f(s4.y); o2 += b2f(s4.z); o3 += b2f(s4.w);
    }
    ushort4 o = {f2b(o0), f2b(o1), f2b(o2), f2b(o3)};
    *(ushort4*)(out + base) = o;
}

// ---------------------------------------------------------------------------
// Final tiny layer: out[N,2] = m2[N,96] @ W3[96,2] + b3
// ---------------------------------------------------------------------------
__global__ void mlp3(const unsigned short* __restrict__ m2, const float* __restrict__ W3,
                     const float* __restrict__ b3, float* __restrict__ out, int N)
{
    int n = blockIdx.x * 256 + threadIdx.x;
    if (n >= N) return;
    float a0 = b3[0], a1 = b3[1];
    const unsigned short* r = m2 + (long)n * 96;
    #pragma unroll 4
    for (int k = 0; k < 96; ++k) {
        float v = b2f(r[k]);
        a0 += v * W3[k * 2];
        a1 += v * W3[k * 2 + 1];
    }
    out[n * 2 + 0] = a0;
    out[n * 2 + 1] = a1;
}

// ---------------------------------------------------------------------------
extern "C" void kernel_launch(void* const* d_in, const int* in_sizes, int n_in,
                              void* d_out, int out_size, void* d_ws, size_t ws_size,
                              hipStream_t stream)
{
    const float* x     = (const float*)d_in[0];
    const int*   ei    = (const int*)d_in[1];
    const float* W_in  = (const float*)d_in[2];
    const float* b_in  = (const float*)d_in[3];
    const float* bn0_g = (const float*)d_in[4];
    const float* bn0_b = (const float*)d_in[5];
    const float* Wl    = (const float*)d_in[6];
    const float* bl    = (const float*)d_in[7];
    const float* Wr    = (const float*)d_in[8];
    const float* bn_g  = (const float*)d_in[9];
    const float* bn_b  = (const float*)d_in[10];
    const float* Wskip = (const float*)d_in[11];
    const float* bskip = (const float*)d_in[12];
    const float* W1    = (const float*)d_in[13];
    const float* b1    = (const float*)d_in[14];
    const float* W2    = (const float*)d_in[15];
    const float* b2    = (const float*)d_in[16];
    const float* W3    = (const float*)d_in[17];
    const float* b3    = (const float*)d_in[18];

    const int DIN = 256;
    const int N = in_sizes[0] / DIN;
    const int E = in_sizes[1] / 2;
    const int* row = ei;
    const int* col = ei + E;
    const long NH = (long)N * H;

    // workspace layout
    float*          tmp      = (float*)d_ws;            // [N,H] fp32 (BN input)
    unsigned short* hb       = (unsigned short*)(tmp + NH);       // [N,H] bf16
    unsigned short* aggb     = hb + NH;                           // [N,H] bf16
    float*          inv      = (float*)(aggb + NH);
    float*          bnsum    = inv + N;
    float*          bnsq     = bnsum + H;
    float*          bnscale  = bnsq + H;
    float*          bnshift  = bnscale + H;
    int*            offs     = (int*)(bnshift + H);     // N+1
    int*            csr_rows = offs + (N + 1);          // E
    unsigned short* Wint     = (unsigned short*)(csr_rows + E);   // [H,DIN]
    unsigned short* Wlt      = Wint + (long)H * DIN;              // 6 [H,H]
    unsigned short* Wrt      = Wlt + 6L * H * H;
    unsigned short* Wskipt   = Wrt + 6L * H * H;                  // 3 [H,H]
    unsigned short* W1t      = Wskipt + 3L * H * H;               // [192,H]
    unsigned short* W2t      = W1t + 192L * H;                    // [96,192]
    // transient CSR scratch aliased into tmp (free until first GEMM)
    int* cnt    = (int*)tmp;
    int* cursor = cnt + N;
    float* out  = (float*)d_out;

    dim3 blk(256);
    const int rg128 = (N + 127) / 128;
    const int app_grid = (int)((NH / 4 + 255) / 256);

    // ---- CSR build
    hipMemsetAsync(cnt, 0, 2 * N * sizeof(int), stream);
    count_edges_i<<<(E + 255) / 256, blk, 0, stream>>>(col, cnt, E);
    exscan_csr<<<1, 1024, 0, stream>>>(cnt, offs, N);
    inv_from_cnt<<<(N + 255) / 256, blk, 0, stream>>>(cnt, inv, N);
    fill_csr<<<(E + 255) / 256, blk, 0, stream>>>(row, col, offs, cursor, csr_rows, E);

    // ---- weight convert+transpose to bf16 [M,K]
    {
        int n1 = H * DIN;
        wt_convert<<<(n1 + 255) / 256, blk, 0, stream>>>(W_in, Wint, n1, DIN, H);
        int n2 = 6 * H * H;
        wt_convert<<<(n2 + 255) / 256, blk, 0, stream>>>(Wl, Wlt, n2, H, H);
        wt_convert<<<(n2 + 255) / 256, blk, 0, stream>>>(Wr, Wrt, n2, H, H);
        int n3 = 3 * H * H;
        wt_convert<<<(n3 + 255) / 256, blk, 0, stream>>>(Wskip, Wskipt, n3, H, H);
        int n4 = H * 192;
        wt_convert<<<(n4 + 255) / 256, blk, 0, stream>>>(W1, W1t, n4, H, 192);
        int n5 = 192 * 96;
        wt_convert<<<(n5 + 255) / 256, blk, 0, stream>>>(W2, W2t, n5, 192, 96);
    }

    // ---- input layer: xb (into aggb) -> GEMM -> BN0 -> hb
    {
        int n4 = N * DIN / 4;
        f2b_vec<<<(n4 + 255) / 256, blk, 0, stream>>>(x, aggb, n4);
    }
    gemm_mfma<<<dim3(rg128, 3), blk, 0, stream>>>(
        aggb, Wint, nullptr, nullptr, b_in, tmp, nullptr, N, DIN, H, 0);
    hipMemsetAsync(bnsum, 0, 2 * H * sizeof(float), stream);
    bn_stats<<<256, H, 0, stream>>>(tmp, bnsum, bnsq, N);
    bn_finalize<<<1, H, 0, stream>>>(bnsum, bnsq, bn0_g, bn0_b, bnscale, bnshift, N);
    bn_apply<<<app_grid, blk, 0, stream>>>(tmp, bnscale, bnshift, nullptr, hb, (int)(NH / 4));

    // ---- 6 SAGE layers
    int skip_idx = 0;
    for (int i = 0; i < 6; ++i) {
        agg_gather<<<(N + 3) / 4, 384, 0, stream>>>(hb, csr_rows, offs, inv, aggb, N);

        gemm_mfma<<<dim3(rg128, 3), blk, 0, stream>>>(
            aggb, Wlt + (long)i * H * H, hb, Wrt + (long)i * H * H,
            bl + i * H, tmp, nullptr, N, H, H, 0);

        hipMemsetAsync(bnsum, 0, 2 * H * sizeof(float), stream);
        bn_stats<<<256, H, 0, stream>>>(tmp, bnsum, bnsq, N);
        bn_finalize<<<1, H, 0, stream>>>(bnsum, bnsq, bn_g + i * H, bn_b + i * H,
                                         bnscale, bnshift, N);

        const unsigned short* S = nullptr;
        if ((i & 1) == 1) {
            gemm_mfma<<<dim3(rg128, 3), blk, 0, stream>>>(
                hb, Wskipt + (long)skip_idx * H * H, nullptr, nullptr,
                bskip + skip_idx * H, nullptr, aggb, N, H, H, 0);
            skip_idx++;
            S = aggb;
        }
        bn_apply<<<app_grid, blk, 0, stream>>>(tmp, bnscale, bnshift, S, hb, (int)(NH / 4));
    }

    // ---- MLP head
    unsigned short* m1b = aggb;                   // [N,192] bf16
    unsigned short* m2b = (unsigned short*)tmp;   // [N,96] bf16
    gemm_mfma<<<dim3(rg128, 2), blk, 0, stream>>>(
        hb, W1t, nullptr, nullptr, b1, nullptr, m1b, N, H, 192, 1);
    gemm_mfma<<<dim3(rg128, 1), blk, 0, stream>>>(
        m1b, W2t, nullptr, nullptr, b2, nullptr, m2b, N, 192, 96, 1);
    mlp3<<<(N + 255) / 256, blk, 0, stream>>>(m2b, W3, b3, out, N);

    // ---- embeddings (bf16 -> fp32)
    b2f_vec<<<(int)(NH / 4 + 255) / 256, blk, 0, stream>>>(hb, out + (long)N * 2, (int)(NH / 4));
}

// Round 4
// 2027.067 us; speedup vs baseline: 14.7841x; 1.0999x over previous
//
#include <hip/hip_runtime.h>

#define H 384
#define EPS 1e-5f

typedef __attribute__((ext_vector_type(8))) short bf8v;            // 8 bf16
typedef __attribute__((ext_vector_type(8))) unsigned short us8;
typedef __attribute__((ext_vector_type(4))) float f32x4;

__device__ __forceinline__ float b2f(unsigned short b) {
    return __builtin_bit_cast(float, (unsigned)b << 16);
}
__device__ __forceinline__ unsigned short f2b(float f) {
    unsigned u = __builtin_bit_cast(unsigned, f);
    u += 0x7FFFu + ((u >> 16) & 1u);          // RNE
    return (unsigned short)(u >> 16);
}

// ---------------------------------------------------------------------------
// bf16 MFMA GEMM: C = A1@W1t^T [+ A2@W2t^T] + bias.
//   SKIP: additionally S_out = A2@W3t^T + bias3 (bf16, no relu), sharing A2 tiles.
//   stats: per-column sum/sumsq of (acc+bias) atomically added to bnsum/bnsq.
// A [Nr,K] bf16 row-major; Wt [M,K] bf16 row-major. 128x128 tile, 4 waves.
// ---------------------------------------------------------------------------
template <bool SKIP>
__global__ __launch_bounds__(256) void gemm_mfma(
    const unsigned short* __restrict__ A1, const unsigned short* __restrict__ W1t,
    const unsigned short* __restrict__ A2, const unsigned short* __restrict__ W2t,
    const unsigned short* __restrict__ W3t, const float* __restrict__ bias3,
    unsigned short* __restrict__ S_out,
    const float* __restrict__ bias, float* __restrict__ Cf,
    unsigned short* __restrict__ Cb,
    float* __restrict__ bnsum, float* __restrict__ bnsq,
    int Nr, int K, int M, int relu)
{
    __shared__ unsigned short As[128][40];   // +8 pad: 80B row stride
    __shared__ unsigned short Bs[128][40];
    __shared__ unsigned short Bs2[SKIP ? 128 : 1][40];
    __shared__ float s_stat[256];            // 128 sum + 128 sumsq
    const int t = threadIdx.x;
    const int wave = t >> 6, lane = t & 63;
    const int wr = (wave >> 1) * 64, wc = (wave & 1) * 64;
    const int r0 = blockIdx.x * 128, c0 = blockIdx.y * 128;
    const int lm = lane & 15, lq = lane >> 4;
    f32x4 acc[4][4] = {};
    f32x4 accS[4][4] = {};

    const int npass = (A2 != nullptr) ? 2 : 1;
    for (int pass = 0; pass < npass; ++pass) {
        const unsigned short* __restrict__ A = pass ? A2 : A1;
        const unsigned short* __restrict__ W = pass ? W2t : W1t;
        for (int k0 = 0; k0 < K; k0 += 32) {
            #pragma unroll
            for (int q = 0; q < 2; ++q) {
                int c = t + q * 256;
                int r = c >> 2, ko = (c & 3) * 8;
                int gr = r0 + r; if (gr >= Nr) gr = Nr - 1;
                *(bf8v*)&As[r][ko] = *(const bf8v*)(A + (long)gr * K + k0 + ko);
            }
            #pragma unroll
            for (int q = 0; q < 2; ++q) {
                int c = t + q * 256;
                int r = c >> 2, ko = (c & 3) * 8;
                int gc = c0 + r; if (gc >= M) gc = M - 1;
                *(bf8v*)&Bs[r][ko] = *(const bf8v*)(W + (long)gc * K + k0 + ko);
            }
            if (SKIP && pass == 1) {
                #pragma unroll
                for (int q = 0; q < 2; ++q) {
                    int c = t + q * 256;
                    int r = c >> 2, ko = (c & 3) * 8;
                    int gc = c0 + r; if (gc >= M) gc = M - 1;
                    *(bf8v*)&Bs2[r][ko] = *(const bf8v*)(W3t + (long)gc * K + k0 + ko);
                }
            }
            __syncthreads();
            bf8v af[4], bf[4];
            #pragma unroll
            for (int i = 0; i < 4; ++i)
                af[i] = *(const bf8v*)&As[wr + i * 16 + lm][lq * 8];
            #pragma unroll
            for (int j = 0; j < 4; ++j)
                bf[j] = *(const bf8v*)&Bs[wc + j * 16 + lm][lq * 8];
            #pragma unroll
            for (int i = 0; i < 4; ++i)
                #pragma unroll
                for (int j = 0; j < 4; ++j)
                    acc[i][j] = __builtin_amdgcn_mfma_f32_16x16x32_bf16(
                        af[i], bf[j], acc[i][j], 0, 0, 0);
            if (SKIP && pass == 1) {
                bf8v bf2[4];
                #pragma unroll
                for (int j = 0; j < 4; ++j)
                    bf2[j] = *(const bf8v*)&Bs2[wc + j * 16 + lm][lq * 8];
                #pragma unroll
                for (int i = 0; i < 4; ++i)
                    #pragma unroll
                    for (int j = 0; j < 4; ++j)
                        accS[i][j] = __builtin_amdgcn_mfma_f32_16x16x32_bf16(
                            af[i], bf2[j], accS[i][j], 0, 0, 0);
            }
            __syncthreads();
        }
    }

    const bool do_stats = (bnsum != nullptr);
    if (do_stats) {
        if (t < 256) s_stat[t] = 0.f;
        __syncthreads();
    }

    #pragma unroll
    for (int j = 0; j < 4; ++j) {
        int lcol = wc + j * 16 + lm;
        int col = c0 + lcol;
        if (col >= M) continue;
        float bi = bias[col];
        float bi3 = SKIP ? bias3[col] : 0.f;
        float ls = 0.f, lss = 0.f;
        #pragma unroll
        for (int i = 0; i < 4; ++i) {
            #pragma unroll
            for (int r = 0; r < 4; ++r) {
                int rowi = r0 + wr + i * 16 + lq * 4 + r;
                if (rowi >= Nr) continue;
                float v = acc[i][j][r] + bi;
                ls += v; lss += v * v;
                float vo = relu ? fmaxf(v, 0.f) : v;
                if (Cf) Cf[(long)rowi * M + col] = vo;
                else    Cb[(long)rowi * M + col] = f2b(vo);
                if (SKIP)
                    S_out[(long)rowi * M + col] = f2b(accS[i][j][r] + bi3);
            }
        }
        if (do_stats) {
            atomicAdd(&s_stat[lcol], ls);
            atomicAdd(&s_stat[128 + lcol], lss);
        }
    }
    if (do_stats) {
        __syncthreads();
        if (t < 128) {
            int col = c0 + t;
            if (col < M) {
                atomicAdd(&bnsum[col], s_stat[t]);
                atomicAdd(&bnsq[col], s_stat[128 + t]);
            }
        }
    }
}

// ---------------------------------------------------------------------------
// Weight convert+transpose: W [L][K][M] fp32 -> Wt [L][M][K] bf16
// ---------------------------------------------------------------------------
__global__ void wt_convert(const float* __restrict__ W, unsigned short* __restrict__ Wt,
                           int total, int K, int M)
{
    int idx = blockIdx.x * 256 + threadIdx.x;
    if (idx >= total) return;
    int l = idx / (K * M), rem = idx - l * K * M;
    int k = rem / M, m = rem - k * M;
    Wt[(long)l * K * M + (long)m * K + k] = f2b(W[idx]);
}

__global__ void f2b_vec(const float* __restrict__ X, unsigned short* __restrict__ Y, int n4)
{
    int idx = blockIdx.x * 256 + threadIdx.x;
    if (idx >= n4) return;
    float4 v = *(const float4*)(X + idx * 4);
    ushort4 o = {f2b(v.x), f2b(v.y), f2b(v.z), f2b(v.w)};
    *(ushort4*)(Y + idx * 4) = o;
}

// ---------------------------------------------------------------------------
// CSR construction
// ---------------------------------------------------------------------------
__global__ void count_edges_i(const int* __restrict__ col, int* __restrict__ cnt, int E)
{
    int e = blockIdx.x * 256 + threadIdx.x;
    if (e < E) atomicAdd(&cnt[col[e]], 1);
}

__global__ __launch_bounds__(1024) void exscan_csr(const int* __restrict__ cnt,
                                                   int* __restrict__ offs, int n)
{
    __shared__ int s[1024];
    const int t = threadIdx.x;
    const int chunk = (n + 1023) >> 10;
    int lo = t * chunk, hi = lo + chunk;
    if (lo > n) lo = n;
    if (hi > n) hi = n;
    int sum = 0;
    for (int i = lo; i < hi; ++i) sum += cnt[i];
    s[t] = sum;
    __syncthreads();
    for (int d = 1; d < 1024; d <<= 1) {
        int o = (t >= d) ? s[t - d] : 0;
        __syncthreads();
        s[t] += o;
        __syncthreads();
    }
    int base = (t == 0) ? 0 : s[t - 1];
    for (int i = lo; i < hi; ++i) { offs[i] = base; base += cnt[i]; }
    if (t == 1023) offs[n] = s[1023];
}

__global__ void fill_csr(const int* __restrict__ row, const int* __restrict__ col,
                         const int* __restrict__ offs, int* __restrict__ cursor,
                         int* __restrict__ csr_rows, int E)
{
    int e = blockIdx.x * 256 + threadIdx.x;
    if (e < E) {
        int c = col[e];
        int p = offs[c] + atomicAdd(&cursor[c], 1);
        csr_rows[p] = row[e];
    }
}

__global__ void inv_from_cnt(const int* __restrict__ cnt, float* __restrict__ inv, int n)
{
    int i = blockIdx.x * 256 + threadIdx.x;
    if (i < n) inv[i] = 1.0f / fmaxf((float)cnt[i], 1.0f);
}

// ---------------------------------------------------------------------------
// CSR gather-mean in bf16: 8 nodes/block, 48 lanes/node, ushort8 per lane
// ---------------------------------------------------------------------------
__global__ __launch_bounds__(384) void agg_gather(
    const unsigned short* __restrict__ hb, const int* __restrict__ csr_rows,
    const int* __restrict__ offs, const float* __restrict__ inv,
    unsigned short* __restrict__ aggb, int N)
{
    int g = threadIdx.x / 48;
    int lane = threadIdx.x - g * 48;
    int node = blockIdx.x * 8 + g;
    if (node >= N) return;
    const int lo = offs[node], hi = offs[node + 1];
    float s[8] = {};
    int e = lo;
    for (; e + 1 < hi; e += 2) {
        int r0 = csr_rows[e], r1 = csr_rows[e + 1];
        us8 v0 = *(const us8*)(hb + (long)r0 * H + lane * 8);
        us8 v1 = *(const us8*)(hb + (long)r1 * H + lane * 8);
        #pragma unroll
        for (int q = 0; q < 8; ++q) s[q] += b2f(v0[q]) + b2f(v1[q]);
    }
    if (e < hi) {
        us8 v = *(const us8*)(hb + (long)csr_rows[e] * H + lane * 8);
        #pragma unroll
        for (int q = 0; q < 8; ++q) s[q] += b2f(v[q]);
    }
    float sc = inv[node];
    us8 o;
    #pragma unroll
    for (int q = 0; q < 8; ++q) o[q] = f2b(s[q] * sc);
    *(us8*)(aggb + (long)node * H + lane * 8) = o;
}

// ---------------------------------------------------------------------------
// Fused BN finalize+apply: out_b = relu(X*scale+shift) [+S]; optional fp32 copy
// ---------------------------------------------------------------------------
__global__ __launch_bounds__(256) void bn_apply(
    const float* __restrict__ X, const float* __restrict__ bnsum,
    const float* __restrict__ bnsq, const float* __restrict__ g,
    const float* __restrict__ b, const unsigned short* __restrict__ S,
    unsigned short* __restrict__ outb, float* __restrict__ outf,
    int Nr, int total4)
{
    __shared__ float sc[H], sh[H];
    const int t = threadIdx.x;
    for (int j = t; j < H; j += 256) {
        float mu  = bnsum[j] / (float)Nr;
        float var = bnsq[j] / (float)Nr - mu * mu;
        float s   = g[j] * rsqrtf(fmaxf(var, 0.f) + EPS);
        sc[j] = s;
        sh[j] = b[j] - mu * s;
    }
    __syncthreads();
    int idx = blockIdx.x * 256 + t;
    if (idx >= total4) return;
    int base = idx * 4;
    int j = base % H;
    float4 v = *(const float4*)(&X[base]);
    float o0 = fmaxf(v.x * sc[j + 0] + sh[j + 0], 0.f);
    float o1 = fmaxf(v.y * sc[j + 1] + sh[j + 1], 0.f);
    float o2 = fmaxf(v.z * sc[j + 2] + sh[j + 2], 0.f);
    float o3 = fmaxf(v.w * sc[j + 3] + sh[j + 3], 0.f);
    if (S) {
        ushort4 s4 = *(const ushort4*)(S + base);
        o0 += b2f(s4.x); o1 += b2f(s4.y); o2 += b2f(s4.z); o3 += b2f(s4.w);
    }
    ushort4 o = {f2b(o0), f2b(o1), f2b(o2), f2b(o3)};
    *(ushort4*)(outb + base) = o;
    if (outf) {
        float4 of = {o0, o1, o2, o3};
        *(float4*)(outf + base) = of;
    }
}

// ---------------------------------------------------------------------------
// Final tiny layer: out[N,2] = m2[N,96] @ W3[96,2] + b3
// ---------------------------------------------------------------------------
__global__ void mlp3(const unsigned short* __restrict__ m2, const float* __restrict__ W3,
                     const float* __restrict__ b3, float* __restrict__ out, int N)
{
    int n = blockIdx.x * 256 + threadIdx.x;
    if (n >= N) return;
    float a0 = b3[0], a1 = b3[1];
    const unsigned short* r = m2 + (long)n * 96;
    #pragma unroll 4
    for (int k = 0; k < 96; ++k) {
        float v = b2f(r[k]);
        a0 += v * W3[k * 2];
        a1 += v * W3[k * 2 + 1];
    }
    out[n * 2 + 0] = a0;
    out[n * 2 + 1] = a1;
}

// ---------------------------------------------------------------------------
extern "C" void kernel_launch(void* const* d_in, const int* in_sizes, int n_in,
                              void* d_out, int out_size, void* d_ws, size_t ws_size,
                              hipStream_t stream)
{
    const float* x     = (const float*)d_in[0];
    const int*   ei    = (const int*)d_in[1];
    const float* W_in  = (const float*)d_in[2];
    const float* b_in  = (const float*)d_in[3];
    const float* bn0_g = (const float*)d_in[4];
    const float* bn0_b = (const float*)d_in[5];
    const float* Wl    = (const float*)d_in[6];
    const float* bl    = (const float*)d_in[7];
    const float* Wr    = (const float*)d_in[8];
    const float* bn_g  = (const float*)d_in[9];
    const float* bn_b  = (const float*)d_in[10];
    const float* Wskip = (const float*)d_in[11];
    const float* bskip = (const float*)d_in[12];
    const float* W1    = (const float*)d_in[13];
    const float* b1    = (const float*)d_in[14];
    const float* W2    = (const float*)d_in[15];
    const float* b2    = (const float*)d_in[16];
    const float* W3    = (const float*)d_in[17];
    const float* b3    = (const float*)d_in[18];

    const int DIN = 256;
    const int N = in_sizes[0] / DIN;
    const int E = in_sizes[1] / 2;
    const int* row = ei;
    const int* col = ei + E;
    const long NH = (long)N * H;

    // workspace layout
    float*          tmp      = (float*)d_ws;                      // [N,H] fp32
    unsigned short* hb       = (unsigned short*)(tmp + NH);       // [N,H] bf16
    unsigned short* aggb     = hb + NH;                           // [N,H] bf16
    unsigned short* Sbuf     = aggb + NH;                         // [N,H] bf16
    float*          inv      = (float*)(Sbuf + NH);
    int*            offs     = (int*)(inv + N);                   // N+1
    int*            csr_rows = offs + (N + 1);                    // E
    int*            cnt      = csr_rows + E;                      // N (zeroed)
    int*            cursor   = cnt + N;                           // N (zeroed)
    float*          stats    = (float*)(cursor + N);              // 14*H (zeroed)
    unsigned short* Wint     = (unsigned short*)(stats + 14 * H); // [H,DIN]
    unsigned short* Wlt      = Wint + (long)H * DIN;              // 6 [H,H]
    unsigned short* Wrt      = Wlt + 6L * H * H;
    unsigned short* Wskipt   = Wrt + 6L * H * H;                  // 3 [H,H]
    unsigned short* W1t      = Wskipt + 3L * H * H;               // [192,H]
    unsigned short* W2t      = W1t + 192L * H;                    // [96,192]
    float* out = (float*)d_out;
    float* emb = out + (long)N * 2;

    dim3 blk(256);
    const int rg128 = (N + 127) / 128;
    const int app_grid = (int)((NH / 4 + 255) / 256);

    // single upfront zero of cnt+cursor+stats
    hipMemsetAsync(cnt, 0, (2L * N + 14 * H) * sizeof(float), stream);

    // ---- CSR build
    count_edges_i<<<(E + 255) / 256, blk, 0, stream>>>(col, cnt, E);
    exscan_csr<<<1, 1024, 0, stream>>>(cnt, offs, N);
    inv_from_cnt<<<(N + 255) / 256, blk, 0, stream>>>(cnt, inv, N);
    fill_csr<<<(E + 255) / 256, blk, 0, stream>>>(row, col, offs, cursor, csr_rows, E);

    // ---- weight convert+transpose
    {
        int n1 = H * DIN;
        wt_convert<<<(n1 + 255) / 256, blk, 0, stream>>>(W_in, Wint, n1, DIN, H);
        int n2 = 6 * H * H;
        wt_convert<<<(n2 + 255) / 256, blk, 0, stream>>>(Wl, Wlt, n2, H, H);
        wt_convert<<<(n2 + 255) / 256, blk, 0, stream>>>(Wr, Wrt, n2, H, H);
        int n3 = 3 * H * H;
        wt_convert<<<(n3 + 255) / 256, blk, 0, stream>>>(Wskip, Wskipt, n3, H, H);
        int n4 = H * 192;
        wt_convert<<<(n4 + 255) / 256, blk, 0, stream>>>(W1, W1t, n4, H, 192);
        int n5 = 192 * 96;
        wt_convert<<<(n5 + 255) / 256, blk, 0, stream>>>(W2, W2t, n5, 192, 96);
    }

    // ---- input layer: x->bf16 -> GEMM(+stats0) -> bn_apply -> hb
    {
        int n4 = N * DIN / 4;
        f2b_vec<<<(n4 + 255) / 256, blk, 0, stream>>>(x, aggb, n4);
    }
    gemm_mfma<false><<<dim3(rg128, 3), blk, 0, stream>>>(
        aggb, Wint, nullptr, nullptr, nullptr, nullptr, nullptr,
        b_in, tmp, nullptr, stats, stats + H, N, DIN, H, 0);
    bn_apply<<<app_grid, blk, 0, stream>>>(
        tmp, stats, stats + H, bn0_g, bn0_b, nullptr, hb, nullptr, N, (int)(NH / 4));

    // ---- 6 SAGE layers
    int skip_idx = 0;
    for (int i = 0; i < 6; ++i) {
        float* bs = stats + (i + 1) * 2 * H;
        agg_gather<<<(N + 7) / 8, 384, 0, stream>>>(hb, csr_rows, offs, inv, aggb, N);

        if ((i & 1) == 1) {
            gemm_mfma<true><<<dim3(rg128, 3), blk, 0, stream>>>(
                aggb, Wlt + (long)i * H * H, hb, Wrt + (long)i * H * H,
                Wskipt + (long)skip_idx * H * H, bskip + skip_idx * H, Sbuf,
                bl + i * H, tmp, nullptr, bs, bs + H, N, H, H, 0);
            skip_idx++;
            bn_apply<<<app_grid, blk, 0, stream>>>(
                tmp, bs, bs + H, bn_g + i * H, bn_b + i * H, Sbuf, hb,
                (i == 5) ? emb : nullptr, N, (int)(NH / 4));
        } else {
            gemm_mfma<false><<<dim3(rg128, 3), blk, 0, stream>>>(
                aggb, Wlt + (long)i * H * H, hb, Wrt + (long)i * H * H,
                nullptr, nullptr, nullptr,
                bl + i * H, tmp, nullptr, bs, bs + H, N, H, H, 0);
            bn_apply<<<app_grid, blk, 0, stream>>>(
                tmp, bs, bs + H, bn_g + i * H, bn_b + i * H, nullptr, hb,
                nullptr, N, (int)(NH / 4));
        }
    }

    // ---- MLP head
    unsigned short* m1b = aggb;                   // [N,192] bf16
    unsigned short* m2b = (unsigned short*)tmp;   // [N,96] bf16
    gemm_mfma<false><<<dim3(rg128, 2), blk, 0, stream>>>(
        hb, W1t, nullptr, nullptr, nullptr, nullptr, nullptr,
        b1, nullptr, m1b, nullptr, nullptr, N, H, 192, 1);
    gemm_mfma<false><<<dim3(rg128, 1), blk, 0, stream>>>(
        m1b, W2t, nullptr, nullptr, nullptr, nullptr, nullptr,
        b2, nullptr, m2b, nullptr, nullptr, N, 192, 96, 1);
    mlp3<<<(N + 255) / 256, blk, 0, stream>>>(m2b, W3, b3, out, N);
}

// Round 5
// 1857.806 us; speedup vs baseline: 16.1311x; 1.0911x over previous
//
#include <hip/hip_runtime.h>

#define H 384
#define EPS 1e-5f

typedef __attribute__((ext_vector_type(8))) short bf8v;            // 8 bf16
typedef __attribute__((ext_vector_type(8))) unsigned short us8;
typedef __attribute__((ext_vector_type(4))) float f32x4;

__device__ __forceinline__ float b2f(unsigned short b) {
    return __builtin_bit_cast(float, (unsigned)b << 16);
}
__device__ __forceinline__ unsigned short f2b(float f) {
    unsigned u = __builtin_bit_cast(unsigned, f);
    u += 0x7FFFu + ((u >> 16) & 1u);          // RNE
    return (unsigned short)(u >> 16);
}

// ---------------------------------------------------------------------------
// bf16 MFMA GEMM: Cb = A1@W1t^T [+ A2@W2t^T] + bias (bf16 out, optional relu).
// Optional fused BN stats: per-column sum/sumsq of fp32 (acc+bias) -> atomics.
// A [Nr,K] bf16 row-major; Wt [M,K] bf16 row-major. 128x128 tile, 4 waves.
// ---------------------------------------------------------------------------
__global__ __launch_bounds__(256) void gemm_mfma(
    const unsigned short* __restrict__ A1, const unsigned short* __restrict__ W1t,
    const unsigned short* __restrict__ A2, const unsigned short* __restrict__ W2t,
    const float* __restrict__ bias, unsigned short* __restrict__ Cb,
    float* __restrict__ bnsum, float* __restrict__ bnsq,
    int Nr, int K, int M, int relu)
{
    __shared__ unsigned short As[128][40];   // +8 pad: 80B row stride
    __shared__ unsigned short Bs[128][40];
    __shared__ float s_stat[256];            // 128 sum + 128 sumsq
    const int t = threadIdx.x;
    const int wave = t >> 6, lane = t & 63;
    const int wr = (wave >> 1) * 64, wc = (wave & 1) * 64;
    const int r0 = blockIdx.x * 128, c0 = blockIdx.y * 128;
    const int lm = lane & 15, lq = lane >> 4;
    f32x4 acc[4][4] = {};

    const int npass = (A2 != nullptr) ? 2 : 1;
    for (int pass = 0; pass < npass; ++pass) {
        const unsigned short* __restrict__ A = pass ? A2 : A1;
        const unsigned short* __restrict__ W = pass ? W2t : W1t;
        for (int k0 = 0; k0 < K; k0 += 32) {
            #pragma unroll
            for (int q = 0; q < 2; ++q) {
                int c = t + q * 256;
                int r = c >> 2, ko = (c & 3) * 8;
                int gr = r0 + r; if (gr >= Nr) gr = Nr - 1;
                *(bf8v*)&As[r][ko] = *(const bf8v*)(A + (long)gr * K + k0 + ko);
            }
            #pragma unroll
            for (int q = 0; q < 2; ++q) {
                int c = t + q * 256;
                int r = c >> 2, ko = (c & 3) * 8;
                int gc = c0 + r; if (gc >= M) gc = M - 1;
                *(bf8v*)&Bs[r][ko] = *(const bf8v*)(W + (long)gc * K + k0 + ko);
            }
            __syncthreads();
            bf8v af[4], bf[4];
            #pragma unroll
            for (int i = 0; i < 4; ++i)
                af[i] = *(const bf8v*)&As[wr + i * 16 + lm][lq * 8];
            #pragma unroll
            for (int j = 0; j < 4; ++j)
                bf[j] = *(const bf8v*)&Bs[wc + j * 16 + lm][lq * 8];
            #pragma unroll
            for (int i = 0; i < 4; ++i)
                #pragma unroll
                for (int j = 0; j < 4; ++j)
                    acc[i][j] = __builtin_amdgcn_mfma_f32_16x16x32_bf16(
                        af[i], bf[j], acc[i][j], 0, 0, 0);
            __syncthreads();
        }
    }

    const bool do_stats = (bnsum != nullptr);
    if (do_stats) {
        s_stat[t] = 0.f;
        __syncthreads();
    }

    #pragma unroll
    for (int j = 0; j < 4; ++j) {
        int lcol = wc + j * 16 + lm;
        int col = c0 + lcol;
        if (col >= M) continue;
        float bi = bias[col];
        float ls = 0.f, lss = 0.f;
        #pragma unroll
        for (int i = 0; i < 4; ++i) {
            #pragma unroll
            for (int r = 0; r < 4; ++r) {
                int rowi = r0 + wr + i * 16 + lq * 4 + r;
                if (rowi >= Nr) continue;
                float v = acc[i][j][r] + bi;
                ls += v; lss += v * v;
                float vo = relu ? fmaxf(v, 0.f) : v;
                Cb[(long)rowi * M + col] = f2b(vo);
            }
        }
        if (do_stats) {
            atomicAdd(&s_stat[lcol], ls);
            atomicAdd(&s_stat[128 + lcol], lss);
        }
    }
    if (do_stats) {
        __syncthreads();
        if (t < 128) {
            int col = c0 + t;
            if (col < M) {
                atomicAdd(&bnsum[col], s_stat[t]);
                atomicAdd(&bnsq[col], s_stat[128 + t]);
            }
        }
    }
}

// ---------------------------------------------------------------------------
// Weight convert+transpose: W [L][K][M] fp32 -> Wt [L][M][K] bf16
// ---------------------------------------------------------------------------
__global__ void wt_convert(const float* __restrict__ W, unsigned short* __restrict__ Wt,
                           int total, int K, int M)
{
    int idx = blockIdx.x * 256 + threadIdx.x;
    if (idx >= total) return;
    int l = idx / (K * M), rem = idx - l * K * M;
    int k = rem / M, m = rem - k * M;
    Wt[(long)l * K * M + (long)m * K + k] = f2b(W[idx]);
}

__global__ void f2b_vec(const float* __restrict__ X, unsigned short* __restrict__ Y, int n4)
{
    int idx = blockIdx.x * 256 + threadIdx.x;
    if (idx >= n4) return;
    float4 v = *(const float4*)(X + idx * 4);
    ushort4 o = {f2b(v.x), f2b(v.y), f2b(v.z), f2b(v.w)};
    *(ushort4*)(Y + idx * 4) = o;
}

// ---------------------------------------------------------------------------
// CSR construction
// ---------------------------------------------------------------------------
__global__ void count_edges_i(const int* __restrict__ col, int* __restrict__ cnt, int E)
{
    int e = blockIdx.x * 256 + threadIdx.x;
    if (e < E) atomicAdd(&cnt[col[e]], 1);
}

__global__ __launch_bounds__(1024) void exscan_csr(const int* __restrict__ cnt,
                                                   int* __restrict__ offs, int n)
{
    __shared__ int s[1024];
    const int t = threadIdx.x;
    const int chunk = (n + 1023) >> 10;
    int lo = t * chunk, hi = lo + chunk;
    if (lo > n) lo = n;
    if (hi > n) hi = n;
    int sum = 0;
    for (int i = lo; i < hi; ++i) sum += cnt[i];
    s[t] = sum;
    __syncthreads();
    for (int d = 1; d < 1024; d <<= 1) {
        int o = (t >= d) ? s[t - d] : 0;
        __syncthreads();
        s[t] += o;
        __syncthreads();
    }
    int base = (t == 0) ? 0 : s[t - 1];
    for (int i = lo; i < hi; ++i) { offs[i] = base; base += cnt[i]; }
    if (t == 1023) offs[n] = s[1023];
}

__global__ void fill_csr(const int* __restrict__ row, const int* __restrict__ col,
                         const int* __restrict__ offs, int* __restrict__ cursor,
                         int* __restrict__ csr_rows, int E)
{
    int e = blockIdx.x * 256 + threadIdx.x;
    if (e < E) {
        int c = col[e];
        int p = offs[c] + atomicAdd(&cursor[c], 1);
        csr_rows[p] = row[e];
    }
}

__global__ void inv_from_cnt(const int* __restrict__ cnt, float* __restrict__ inv, int n)
{
    int i = blockIdx.x * 256 + threadIdx.x;
    if (i < n) inv[i] = 1.0f / fmaxf((float)cnt[i], 1.0f);
}

// ---------------------------------------------------------------------------
// CSR gather-mean in bf16: 8 nodes/block, 48 lanes/node, us8/lane, unroll x4
// ---------------------------------------------------------------------------
__global__ __launch_bounds__(384) void agg_gather(
    const unsigned short* __restrict__ hb, const int* __restrict__ csr_rows,
    const int* __restrict__ offs, const float* __restrict__ inv,
    unsigned short* __restrict__ aggb, int N)
{
    int g = threadIdx.x / 48;
    int lane = threadIdx.x - g * 48;
    int node = blockIdx.x * 8 + g;
    if (node >= N) return;
    const int lo = offs[node], hi = offs[node + 1];
    float s[8] = {};
    int e = lo;
    for (; e + 3 < hi; e += 4) {
        int r0 = csr_rows[e], r1 = csr_rows[e + 1];
        int r2 = csr_rows[e + 2], r3 = csr_rows[e + 3];
        us8 v0 = *(const us8*)(hb + (long)r0 * H + lane * 8);
        us8 v1 = *(const us8*)(hb + (long)r1 * H + lane * 8);
        us8 v2 = *(const us8*)(hb + (long)r2 * H + lane * 8);
        us8 v3 = *(const us8*)(hb + (long)r3 * H + lane * 8);
        #pragma unroll
        for (int q = 0; q < 8; ++q)
            s[q] += (b2f(v0[q]) + b2f(v1[q])) + (b2f(v2[q]) + b2f(v3[q]));
    }
    for (; e < hi; ++e) {
        us8 v = *(const us8*)(hb + (long)csr_rows[e] * H + lane * 8);
        #pragma unroll
        for (int q = 0; q < 8; ++q) s[q] += b2f(v[q]);
    }
    float sc = inv[node];
    us8 o;
    #pragma unroll
    for (int q = 0; q < 8; ++q) o[q] = f2b(s[q] * sc);
    *(us8*)(aggb + (long)node * H + lane * 8) = o;
}

// ---------------------------------------------------------------------------
// Fused BN finalize+apply: outb = relu(X*scale+shift) [+S]; optional fp32 copy
// X is bf16 (pre-BN); stats were accumulated in fp32 by the GEMM epilogue.
// ---------------------------------------------------------------------------
__global__ __launch_bounds__(256) void bn_apply(
    const unsigned short* __restrict__ X, const float* __restrict__ bnsum,
    const float* __restrict__ bnsq, const float* __restrict__ g,
    const float* __restrict__ b, const unsigned short* __restrict__ S,
    unsigned short* __restrict__ outb, float* __restrict__ outf,
    int Nr, int total4)
{
    __shared__ float sc[H], sh[H];
    const int t = threadIdx.x;
    for (int j = t; j < H; j += 256) {
        float mu  = bnsum[j] / (float)Nr;
        float var = bnsq[j] / (float)Nr - mu * mu;
        float s   = g[j] * rsqrtf(fmaxf(var, 0.f) + EPS);
        sc[j] = s;
        sh[j] = b[j] - mu * s;
    }
    __syncthreads();
    int idx = blockIdx.x * 256 + t;
    if (idx >= total4) return;
    int base = idx * 4;
    int j = base % H;
    ushort4 v = *(const ushort4*)(X + base);
    float o0 = fmaxf(b2f(v.x) * sc[j + 0] + sh[j + 0], 0.f);
    float o1 = fmaxf(b2f(v.y) * sc[j + 1] + sh[j + 1], 0.f);
    float o2 = fmaxf(b2f(v.z) * sc[j + 2] + sh[j + 2], 0.f);
    float o3 = fmaxf(b2f(v.w) * sc[j + 3] + sh[j + 3], 0.f);
    if (S) {
        ushort4 s4 = *(const ushort4*)(S + base);
        o0 += b2f(s4.x); o1 += b2f(s4.y); o2 += b2f(s4.z); o3 += b2f(s4.w);
    }
    ushort4 o = {f2b(o0), f2b(o1), f2b(o2), f2b(o3)};
    *(ushort4*)(outb + base) = o;
    if (outf) {
        float4 of = {o0, o1, o2, o3};
        *(float4*)(outf + base) = of;
    }
}

// ---------------------------------------------------------------------------
// Final tiny layer: out[N,2] = m2[N,96] @ W3[96,2] + b3
// ---------------------------------------------------------------------------
__global__ void mlp3(const unsigned short* __restrict__ m2, const float* __restrict__ W3,
                     const float* __restrict__ b3, float* __restrict__ out, int N)
{
    int n = blockIdx.x * 256 + threadIdx.x;
    if (n >= N) return;
    float a0 = b3[0], a1 = b3[1];
    const unsigned short* r = m2 + (long)n * 96;
    #pragma unroll 4
    for (int k = 0; k < 96; ++k) {
        float v = b2f(r[k]);
        a0 += v * W3[k * 2];
        a1 += v * W3[k * 2 + 1];
    }
    out[n * 2 + 0] = a0;
    out[n * 2 + 1] = a1;
}

// ---------------------------------------------------------------------------
extern "C" void kernel_launch(void* const* d_in, const int* in_sizes, int n_in,
                              void* d_out, int out_size, void* d_ws, size_t ws_size,
                              hipStream_t stream)
{
    const float* x     = (const float*)d_in[0];
    const int*   ei    = (const int*)d_in[1];
    const float* W_in  = (const float*)d_in[2];
    const float* b_in  = (const float*)d_in[3];
    const float* bn0_g = (const float*)d_in[4];
    const float* bn0_b = (const float*)d_in[5];
    const float* Wl    = (const float*)d_in[6];
    const float* bl    = (const float*)d_in[7];
    const float* Wr    = (const float*)d_in[8];
    const float* bn_g  = (const float*)d_in[9];
    const float* bn_b  = (const float*)d_in[10];
    const float* Wskip = (const float*)d_in[11];
    const float* bskip = (const float*)d_in[12];
    const float* W1    = (const float*)d_in[13];
    const float* b1    = (const float*)d_in[14];
    const float* W2    = (const float*)d_in[15];
    const float* b2    = (const float*)d_in[16];
    const float* W3    = (const float*)d_in[17];
    const float* b3    = (const float*)d_in[18];

    const int DIN = 256;
    const int N = in_sizes[0] / DIN;
    const int E = in_sizes[1] / 2;
    const int* row = ei;
    const int* col = ei + E;
    const long NH = (long)N * H;

    // workspace layout (all bf16 feature buffers)
    unsigned short* tmp      = (unsigned short*)d_ws;             // [N,H] pre-BN
    unsigned short* hb       = tmp + NH;                          // [N,H]
    unsigned short* aggb     = hb + NH;                           // [N,H]
    unsigned short* Sbuf     = aggb + NH;                         // [N,H]
    unsigned short* xb       = Sbuf + NH;                         // [N,DIN]
    float*          inv      = (float*)(xb + (long)N * DIN);
    int*            offs     = (int*)(inv + N);                   // N+1
    int*            csr_rows = offs + (N + 1);                    // E
    int*            cnt      = csr_rows + E;                      // N (zeroed)
    int*            cursor   = cnt + N;                           // N (zeroed)
    float*          stats    = (float*)(cursor + N);              // 14*H (zeroed)
    unsigned short* Wint     = (unsigned short*)(stats + 14 * H); // [H,DIN]
    unsigned short* Wlt      = Wint + (long)H * DIN;              // 6 [H,H]
    unsigned short* Wrt      = Wlt + 6L * H * H;
    unsigned short* Wskipt   = Wrt + 6L * H * H;                  // 3 [H,H]
    unsigned short* W1t      = Wskipt + 3L * H * H;               // [192,H]
    unsigned short* W2t      = W1t + 192L * H;                    // [96,192]
    float* out = (float*)d_out;
    float* emb = out + (long)N * 2;

    dim3 blk(256);
    const int rg128 = (N + 127) / 128;
    const int app_grid = (int)((NH / 4 + 255) / 256);

    // single upfront zero of cnt+cursor+stats
    hipMemsetAsync(cnt, 0, (2L * N + 14 * H) * sizeof(float), stream);

    // ---- CSR build
    count_edges_i<<<(E + 255) / 256, blk, 0, stream>>>(col, cnt, E);
    exscan_csr<<<1, 1024, 0, stream>>>(cnt, offs, N);
    inv_from_cnt<<<(N + 255) / 256, blk, 0, stream>>>(cnt, inv, N);
    fill_csr<<<(E + 255) / 256, blk, 0, stream>>>(row, col, offs, cursor, csr_rows, E);

    // ---- weight convert+transpose
    {
        int n1 = H * DIN;
        wt_convert<<<(n1 + 255) / 256, blk, 0, stream>>>(W_in, Wint, n1, DIN, H);
        int n2 = 6 * H * H;
        wt_convert<<<(n2 + 255) / 256, blk, 0, stream>>>(Wl, Wlt, n2, H, H);
        wt_convert<<<(n2 + 255) / 256, blk, 0, stream>>>(Wr, Wrt, n2, H, H);
        int n3 = 3 * H * H;
        wt_convert<<<(n3 + 255) / 256, blk, 0, stream>>>(Wskip, Wskipt, n3, H, H);
        int n4 = H * 192;
        wt_convert<<<(n4 + 255) / 256, blk, 0, stream>>>(W1, W1t, n4, H, 192);
        int n5 = 192 * 96;
        wt_convert<<<(n5 + 255) / 256, blk, 0, stream>>>(W2, W2t, n5, 192, 96);
    }

    // ---- input layer: x->bf16 -> GEMM(+stats0) -> bn_apply -> hb
    {
        int n4 = N * DIN / 4;
        f2b_vec<<<(n4 + 255) / 256, blk, 0, stream>>>(x, xb, n4);
    }
    gemm_mfma<<<dim3(rg128, 3), blk, 0, stream>>>(
        xb, Wint, nullptr, nullptr, b_in, tmp, stats, stats + H, N, DIN, H, 0);
    bn_apply<<<app_grid, blk, 0, stream>>>(
        tmp, stats, stats + H, bn0_g, bn0_b, nullptr, hb, nullptr, N, (int)(NH / 4));

    // ---- 6 SAGE layers
    int skip_idx = 0;
    for (int i = 0; i < 6; ++i) {
        float* bs = stats + (i + 1) * 2 * H;
        agg_gather<<<(N + 7) / 8, 384, 0, stream>>>(hb, csr_rows, offs, inv, aggb, N);

        // tmp = agg@Wl + h@Wr + bl  (+ fused BN stats)
        gemm_mfma<<<dim3(rg128, 3), blk, 0, stream>>>(
            aggb, Wlt + (long)i * H * H, hb, Wrt + (long)i * H * H,
            bl + i * H, tmp, bs, bs + H, N, H, H, 0);

        const unsigned short* S = nullptr;
        if ((i & 1) == 1) {
            // separate skip GEMM: Sbuf = h@Wskip + bskip (no stats, 64-VGPR acc)
            gemm_mfma<<<dim3(rg128, 3), blk, 0, stream>>>(
                hb, Wskipt + (long)skip_idx * H * H, nullptr, nullptr,
                bskip + skip_idx * H, Sbuf, nullptr, nullptr, N, H, H, 0);
            skip_idx++;
            S = Sbuf;
        }
        bn_apply<<<app_grid, blk, 0, stream>>>(
            tmp, bs, bs + H, bn_g + i * H, bn_b + i * H, S, hb,
            (i == 5) ? emb : nullptr, N, (int)(NH / 4));
    }

    // ---- MLP head
    unsigned short* m1b = aggb;    // [N,192] bf16
    unsigned short* m2b = tmp;     // [N,96] bf16
    gemm_mfma<<<dim3(rg128, 2), blk, 0, stream>>>(
        hb, W1t, nullptr, nullptr, b1, m1b, nullptr, nullptr, N, H, 192, 1);
    gemm_mfma<<<dim3(rg128, 1), blk, 0, stream>>>(
        m1b, W2t, nullptr, nullptr, b2, m2b, nullptr, nullptr, N, 192, 96, 1);
    mlp3<<<(N + 255) / 256, blk, 0, stream>>>(m2b, W3, b3, out, N);
}